// Round 5
// baseline (828.634 us; speedup 1.0000x reference)
//
#include <hip/hip_runtime.h>

// CropAndResize: image (8,256,200,200) fp32, boxes (N,4), box_ind (N,) ->
// out (N,256,14,14) fp32.
// R7 = R6 resubmit (previous bench died in infra: "container failed twice";
// no counters were produced, kernel re-audited for deadlock/OOB — clean).
// R6 rationale: R5 falsified the MLP theory (28 in-flight gathers -> slower,
// more fetch => TA/L1-bound). Replace the scattered gather entirely: per
// (box,channel) the bilinear taps live in <=28 image rows x one column span.
// Stage those row segments into LDS with stride-1 coalesced loads (4 deep in
// flight), then "gather" from LDS and store coalesced. Every global line is
// fetched once per channel and fully used.
// Kept: counting-sort by image, chunk-major block order, bijective XCD
// swizzle. All resident blocks sweep channels in lockstep -> per-XCD L2
// working set stays ~1-2MB (<4MB).

#define CROP_H 14
#define CROP_W 14
#define CROP_HW (CROP_H * CROP_W)           // 196
#define C_DIM 256
#define H_DIM 200
#define W_DIM 200
#define HW (H_DIM * W_DIM)
#define PER_BOX (C_DIM * CROP_HW)           // 50176
#define BLOCK 256
#define CHUNKS 4
#define C_PER (C_DIM / CHUNKS)              // 64 channels per block
#define NSLOT (2 * CROP_H)                  // 28 staged row-slots (14x top,bot)
#define MAXW 201                            // max col-span 200, +1 so stride can be odd
#define NXCD 8

__global__ __launch_bounds__(BLOCK) void sort_boxes_kernel(
    const int* __restrict__ box_ind, int N, int* __restrict__ perm)
{
    __shared__ int cnt[8];
    __shared__ int base[8];
    const int t = threadIdx.x;
    if (t < 8) cnt[t] = 0;
    __syncthreads();
    for (int i = t; i < N; i += BLOCK) atomicAdd(&cnt[box_ind[i]], 1);
    __syncthreads();
    if (t == 0) {
        int run = 0;
        for (int b = 0; b < 8; ++b) { base[b] = run; run += cnt[b]; }
    }
    __syncthreads();
    for (int i = t; i < N; i += BLOCK) {
        const int pos = atomicAdd(&base[box_ind[i]], 1);
        perm[pos] = i;
    }
}

__global__ __launch_bounds__(BLOCK, 7) void crop_and_resize_kernel(
    const float* __restrict__ image,
    const float* __restrict__ boxes,
    const int*   __restrict__ box_ind,
    const int*   __restrict__ perm,
    float*       __restrict__ out,
    int N)
{
    __shared__ float s_tile[NSLOT * MAXW];   // 22512 B row-segment tile
    __shared__ int   s_rowoff[NSLOT];        // row*W (then +minli after fixup)
    __shared__ int   s_li[CROP_W], s_dr[CROP_W];
    __shared__ float s_ly[CROP_H], s_lx[CROP_W];
    __shared__ float s_vy[CROP_H], s_vx[CROP_W];
    __shared__ int   s_n, s_b, s_minli, s_span, s_sw;
    __shared__ unsigned s_magic;

    // Bijective XCD swizzle + chunk-major ordering.
    const int nwg = gridDim.x;
    int wgid = blockIdx.x;
    if ((nwg % NXCD) == 0) {
        const int per = nwg / NXCD;
        wgid = (wgid % NXCD) * per + wgid / NXCD;
    }
    const int chunk = wgid / N;
    const int slot  = wgid - chunk * N;
    const int t     = threadIdx.x;

    if (t == 0) { const int nn = perm[slot]; s_n = nn; s_b = box_ind[nn]; }
    __syncthreads();
    const int n = s_n;

    if (t < CROP_H + CROP_W) {
        const float y1 = boxes[n * 4 + 0];
        const float x1 = boxes[n * 4 + 1];
        const float y2 = boxes[n * 4 + 2];
        const float x2 = boxes[n * 4 + 3];
        if (t < CROP_H) {
            const float hs   = (y2 - y1) * (float)(H_DIM - 1) / (float)(CROP_H - 1);
            const float in_y = y1 * (float)(H_DIM - 1) + (float)t * hs;
            const float top  = floorf(in_y);
            int ti = (int)top;
            ti = min(max(ti, 0), H_DIM - 1);
            const int bi = min(ti + 1, H_DIM - 1);
            s_rowoff[2 * t]     = ti * W_DIM;
            s_rowoff[2 * t + 1] = bi * W_DIM;
            s_ly[t] = in_y - top;            // from UNclipped floor (matches ref)
            s_vy[t] = (in_y >= 0.0f && in_y <= (float)(H_DIM - 1)) ? 1.0f : 0.0f;
        } else {
            const int ix = t - CROP_H;
            const float ws   = (x2 - x1) * (float)(W_DIM - 1) / (float)(CROP_W - 1);
            const float in_x = x1 * (float)(W_DIM - 1) + (float)ix * ws;
            const float left = floorf(in_x);
            int li = (int)left;
            li = min(max(li, 0), W_DIM - 1);
            const int ri = min(li + 1, W_DIM - 1);
            s_li[ix] = li;
            s_dr[ix] = ri - li;              // 0 or 1
            s_lx[ix] = in_x - left;
            s_vx[ix] = (in_x >= 0.0f && in_x <= (float)(W_DIM - 1)) ? 1.0f : 0.0f;
        }
    }
    __syncthreads();

    if (t == 0) {
        int mn = W_DIM, mx = 0;
        for (int i = 0; i < CROP_W; ++i) {
            mn = min(mn, s_li[i]);
            mx = max(mx, s_li[i] + s_dr[i]);
        }
        const int span = mx - mn + 1;        // 2..200
        s_minli = mn;
        s_span  = span;
        s_sw    = span | 1;                  // odd LDS stride -> banks spread
        s_magic = (unsigned)(0x100000000ULL / (unsigned)span) + 1u; // exact for idx < 2^24
    }
    __syncthreads();
    const int minli = s_minli;
    if (t < NSLOT) s_rowoff[t] += minli;     // rowoff = row*W + minli
    __syncthreads();

    const int span = s_span;
    const int sw   = s_sw;
    const unsigned magic = s_magic;
    const int T    = NSLOT * span;           // total staged floats (<=5600)
    const int Tm1  = T - 1;

    const float* __restrict__ imgc =
        image + ((size_t)s_b * C_DIM + (size_t)(chunk * C_PER)) * HW;
    float* __restrict__ outp =
        out + (size_t)n * PER_BOX + (size_t)(chunk * C_PER) * CROP_HW + t;

    // Per-thread compute descriptor (pixel p = t, only t < 196 active).
    const bool act = (t < CROP_HW);
    int topoff = 0, dr = 0;
    float ly = 0.0f, lx = 0.0f, vf = 0.0f;
    if (act) {
        const int iy = t / CROP_W;
        const int ix = t - iy * CROP_W;
        topoff = (2 * iy) * sw + (s_li[ix] - minli);
        dr = s_dr[ix];
        ly = s_ly[iy];
        lx = s_lx[ix];
        vf = s_vy[iy] * s_vx[ix];
    }

    for (int c = 0; c < C_PER; ++c) {
        const float* __restrict__ imgch = imgc + (size_t)c * HW;

        // Stage: 4 coalesced loads in flight per wave (clamped batch; the
        // duplicate writes at the tail store identical values — benign).
        for (int i0 = t; i0 < T; i0 += 4 * BLOCK) {
            const int i1 = min(i0 + 1 * BLOCK, Tm1);
            const int i2 = min(i0 + 2 * BLOCK, Tm1);
            const int i3 = min(i0 + 3 * BLOCK, Tm1);
            const int sa = (int)__umulhi((unsigned)i0, magic);
            const int sb = (int)__umulhi((unsigned)i1, magic);
            const int sc = (int)__umulhi((unsigned)i2, magic);
            const int sd = (int)__umulhi((unsigned)i3, magic);
            const int xa = i0 - sa * span;
            const int xb = i1 - sb * span;
            const int xc = i2 - sc * span;
            const int xd = i3 - sd * span;
            const float va = imgch[s_rowoff[sa] + xa];
            const float vb = imgch[s_rowoff[sb] + xb];
            const float vc = imgch[s_rowoff[sc] + xc];
            const float vd = imgch[s_rowoff[sd] + xd];
            s_tile[sa * sw + xa] = va;
            s_tile[sb * sw + xb] = vb;
            s_tile[sc * sw + xc] = vc;
            s_tile[sd * sw + xd] = vd;
        }
        __syncthreads();

        if (act) {
            const float tl = s_tile[topoff];
            const float tr = s_tile[topoff + dr];
            const float bl = s_tile[topoff + sw];
            const float br = s_tile[topoff + sw + dr];
            const float tv = fmaf(tr - tl, lx, tl);
            const float bv = fmaf(br - bl, lx, bl);
            outp[c * CROP_HW] = fmaf(bv - tv, ly, tv) * vf;
        }
        __syncthreads();
    }
}

extern "C" void kernel_launch(void* const* d_in, const int* in_sizes, int n_in,
                              void* d_out, int out_size, void* d_ws, size_t ws_size,
                              hipStream_t stream) {
    const float* image   = (const float*)d_in[0];
    const float* boxes   = (const float*)d_in[1];
    const int*   box_ind = (const int*)d_in[2];
    float*       out     = (float*)d_out;
    int*         perm    = (int*)d_ws;          // N ints of scratch

    const int N = in_sizes[2];  // number of boxes (1000)

    sort_boxes_kernel<<<dim3(1), dim3(BLOCK), 0, stream>>>(box_ind, N, perm);
    crop_and_resize_kernel<<<dim3(N * CHUNKS), dim3(BLOCK), 0, stream>>>(
        image, boxes, box_ind, perm, out, N);
}